// Round 3
// baseline (1789.435 us; speedup 1.0000x reference)
//
#include <hip/hip_runtime.h>
#include <hip/hip_bf16.h>

#define D_DIM 1024
#define VOCABSZ 32000
#define NROWSZ 4096
#define MBLK 64
#define KVBLK 32
#define LOG2E 1.44269504088896340736f

typedef unsigned short u16;
typedef short s8v __attribute__((ext_vector_type(8)));
typedef float f4v __attribute__((ext_vector_type(4)));

static __device__ __forceinline__ u16 f2bf(float f) {
  union { float f; unsigned int u; } x; x.f = f;
  unsigned int r = x.u + 0x7fffu + ((x.u >> 16) & 1u);
  return (u16)(r >> 16);
}
static __device__ __forceinline__ unsigned int pack2(float lo, float hi) {
  return (unsigned int)f2bf(lo) | ((unsigned int)f2bf(hi) << 16);
}
static __device__ __forceinline__ float bf2f(u16 b) {
  union { unsigned int u; float f; } x; x.u = ((unsigned int)b) << 16;
  return x.f;
}
static __device__ __forceinline__ float bfu_lo(unsigned int u) {
  union { unsigned int u; float f; } x; x.u = u << 16; return x.f;
}
static __device__ __forceinline__ float bfu_hi(unsigned int u) {
  union { unsigned int u; float f; } x; x.u = u & 0xffff0000u; return x.f;
}
// LDS-only barrier: does NOT drain vmcnt, so global prefetches stay in flight.
static __device__ __forceinline__ void bar_lds() {
  asm volatile("s_waitcnt lgkmcnt(0)" ::: "memory");
  __builtin_amdgcn_s_barrier();
}

// ---------------------------------------------------------------------------
// Prep: emb fp32 -> bf16 row-major (Ebf [V][D]) and bf16 transposed (ETbf [D][V])
// ---------------------------------------------------------------------------
__global__ __launch_bounds__(256) void cvt_kernel(const float* __restrict__ emb,
                                                  u16* __restrict__ Ebf,
                                                  u16* __restrict__ ETbf) {
  __shared__ u16 T[64][65];
  const int tile = blockIdx.x;
  const int v0 = (tile / 16) * 64;
  const int d0 = (tile % 16) * 64;
  const int t = threadIdx.x;
#pragma unroll
  for (int k = 0; k < 4; ++k) {
    int cidx = t + 256 * k;
    int vr = cidx >> 4;
    int dq = (cidx & 15) << 2;
    float4 f = *(const float4*)(emb + (size_t)(v0 + vr) * D_DIM + d0 + dq);
    u16 b0 = f2bf(f.x), b1 = f2bf(f.y), b2 = f2bf(f.z), b3 = f2bf(f.w);
    ushort4 rowv; rowv.x = b0; rowv.y = b1; rowv.z = b2; rowv.w = b3;
    *(ushort4*)(Ebf + (size_t)(v0 + vr) * D_DIM + d0 + dq) = rowv;
    T[vr][dq] = b0; T[vr][dq + 1] = b1; T[vr][dq + 2] = b2; T[vr][dq + 3] = b3;
  }
  __syncthreads();
#pragma unroll
  for (int k = 0; k < 4; ++k) {
    int cidx = t + 256 * k;
    int dr = cidx >> 4;
    int vq = (cidx & 15) << 2;
    ushort4 o;
    o.x = T[vq][dr]; o.y = T[vq + 1][dr]; o.z = T[vq + 2][dr]; o.w = T[vq + 3][dr];
    *(ushort4*)(ETbf + (size_t)(d0 + dr) * VOCABSZ + v0 + vq) = o;
  }
}

// ---------------------------------------------------------------------------
// Flash v3: 8 waves, MBLK=64, KV=32 processed as two 16-vocab halves.
// ef register double-buffered (prefetch half h+1 before QK of half h).
// LDS-only barriers keep global prefetch in flight. Sred packed bf16 (16 KB).
// Waves 0-3 own softmax slots (16 rows each); waves 4-7 idle through softmax.
// ---------------------------------------------------------------------------
template <int NSPLIT>
__global__ __launch_bounds__(512, 2) void flash3_kernel(
    const float* __restrict__ qg, const u16* __restrict__ Ebf,
    const u16* __restrict__ ETbf, float* __restrict__ out,
    u16* __restrict__ pctx, float* __restrict__ pstat) {
  __shared__ uint2 Sred[8][4][64];     // 16 KB: bf16x4-packed S^T partials
  __shared__ u16 Plds[MBLK * KVBLK];   // 4 KB, byte ^= (m&6)<<3
  __shared__ float l_lds[MBLK];        // NSPLIT==1 only

  const int tid = threadIdx.x;
  const int w = tid >> 6;
  const int l = tid & 63;
  const int g = l >> 4;
  const int c = l & 15;
  const int bid = blockIdx.x;
  const int sp = (NSPLIT == 4) ? (bid & 3) : 0;
  const int rb = (NSPLIT == 4) ? (bid >> 2) : bid;
  const int row0 = rb * MBLK;
  const int db = w * 128;
  const int vslice = VOCABSZ / NSPLIT;
  const int vbase = sp * vslice;
  const int ntiles = vslice / KVBLK;

  const f4v fzero = {0.f, 0.f, 0.f, 0.f};

  // ---- Q fragments (B-role): qf[mt][kt] = Q[row0+16mt+c][db+32kt+8g+i]
  s8v qf[4][4];
#pragma unroll
  for (int mt = 0; mt < 4; ++mt)
#pragma unroll
    for (int kt = 0; kt < 4; ++kt) {
      const float* src = qg + (size_t)(row0 + 16 * mt + c) * D_DIM + db + 32 * kt + 8 * g;
      float4 a = *(const float4*)src;
      float4 b = *(const float4*)(src + 4);
      s8v v;
      v[0] = (short)f2bf(a.x); v[1] = (short)f2bf(a.y);
      v[2] = (short)f2bf(a.z); v[3] = (short)f2bf(a.w);
      v[4] = (short)f2bf(b.x); v[5] = (short)f2bf(b.y);
      v[6] = (short)f2bf(b.z); v[7] = (short)f2bf(b.w);
      qf[mt][kt] = v;
    }

  f4v acc[4][8];
#pragma unroll
  for (int mt = 0; mt < 4; ++mt)
#pragma unroll
    for (int nt = 0; nt < 8; ++nt) acc[mt][nt] = fzero;

  float lcur = 0.f;

  // prologue: efA = half0 of tile0
  s8v efA[4], efB[4];
#pragma unroll
  for (int kt = 0; kt < 4; ++kt)
    efA[kt] = *(const s8v*)(Ebf + (size_t)(vbase + c) * D_DIM + db + 32 * kt + 8 * g);

  for (int t = 0; t < ntiles; ++t) {
    const int v0 = vbase + t * KVBLK;
    const int v0n = (t + 1 < ntiles) ? (v0 + KVBLK) : vbase;  // clamped next tile

    // ================= half 0 (vocab v0..v0+16) =================
    // prefetch efB = half1 (issue early; LDS-only barriers won't drain it)
#pragma unroll
    for (int kt = 0; kt < 4; ++kt)
      efB[kt] = *(const s8v*)(Ebf + (size_t)(v0 + 16 + c) * D_DIM + db + 32 * kt + 8 * g);

    {
      f4v st[4];
#pragma unroll
      for (int mt = 0; mt < 4; ++mt) st[mt] = fzero;
#pragma unroll
      for (int kt = 0; kt < 4; ++kt)
#pragma unroll
        for (int mt = 0; mt < 4; ++mt)
          st[mt] = __builtin_amdgcn_mfma_f32_16x16x32_bf16(efA[kt], qf[mt][kt], st[mt], 0, 0, 0);
#pragma unroll
      for (int mt = 0; mt < 4; ++mt) {
        uint2 pk; pk.x = pack2(st[mt][0], st[mt][1]); pk.y = pack2(st[mt][2], st[mt][3]);
        Sred[w][mt][l] = pk;
      }
    }
    bar_lds();  // Sred visible

    if (w < 4) {
      float ss0 = 0.f, ss1 = 0.f, ss2 = 0.f, ss3 = 0.f;
#pragma unroll
      for (int ww = 0; ww < 8; ++ww) {
        uint2 u = Sred[ww][w][l];
        ss0 += bfu_lo(u.x); ss1 += bfu_hi(u.x);
        ss2 += bfu_lo(u.y); ss3 += bfu_hi(u.y);
      }
      float p0 = exp2f(ss0 * LOG2E), p1 = exp2f(ss1 * LOG2E);
      float p2 = exp2f(ss2 * LOG2E), p3 = exp2f(ss3 * LOG2E);
      float lp = (p0 + p1) + (p2 + p3);
      lp += __shfl_xor(lp, 16);
      lp += __shfl_xor(lp, 32);
      lcur += lp;
      int m = 16 * w + c;
      int byte = (m * 64 + (0 * 16 + 4 * g) * 2) ^ ((m & 6) << 3);
      uint2 pk; pk.x = pack2(p0, p1); pk.y = pack2(p2, p3);
      *(uint2*)((char*)Plds + byte) = pk;
    }
    bar_lds();  // P half0 visible; Sred reads done (WAR for half1 writes)

    // ================= half 1 (vocab v0+16..v0+32) =================
    // prefetch efA = half0 of next tile
#pragma unroll
    for (int kt = 0; kt < 4; ++kt)
      efA[kt] = *(const s8v*)(Ebf + (size_t)(v0n + c) * D_DIM + db + 32 * kt + 8 * g);

    {
      f4v st[4];
#pragma unroll
      for (int mt = 0; mt < 4; ++mt) st[mt] = fzero;
#pragma unroll
      for (int kt = 0; kt < 4; ++kt)
#pragma unroll
        for (int mt = 0; mt < 4; ++mt)
          st[mt] = __builtin_amdgcn_mfma_f32_16x16x32_bf16(efB[kt], qf[mt][kt], st[mt], 0, 0, 0);
#pragma unroll
      for (int mt = 0; mt < 4; ++mt) {
        uint2 pk; pk.x = pack2(st[mt][0], st[mt][1]); pk.y = pack2(st[mt][2], st[mt][3]);
        Sred[w][mt][l] = pk;
      }
    }
    bar_lds();  // Sred visible

    // prefetch ET fragments for PV (issued before softmax, used after B_b)
    s8v etf[8];
#pragma unroll
    for (int nt = 0; nt < 8; ++nt)
      etf[nt] = *(const s8v*)(ETbf + (size_t)(db + 16 * nt + c) * VOCABSZ + v0 + 8 * g);

    if (w < 4) {
      float ss0 = 0.f, ss1 = 0.f, ss2 = 0.f, ss3 = 0.f;
#pragma unroll
      for (int ww = 0; ww < 8; ++ww) {
        uint2 u = Sred[ww][w][l];
        ss0 += bfu_lo(u.x); ss1 += bfu_hi(u.x);
        ss2 += bfu_lo(u.y); ss3 += bfu_hi(u.y);
      }
      float p0 = exp2f(ss0 * LOG2E), p1 = exp2f(ss1 * LOG2E);
      float p2 = exp2f(ss2 * LOG2E), p3 = exp2f(ss3 * LOG2E);
      float lp = (p0 + p1) + (p2 + p3);
      lp += __shfl_xor(lp, 16);
      lp += __shfl_xor(lp, 32);
      lcur += lp;
      int m = 16 * w + c;
      int byte = (m * 64 + (1 * 16 + 4 * g) * 2) ^ ((m & 6) << 3);
      uint2 pk; pk.x = pack2(p0, p1); pk.y = pack2(p2, p3);
      *(uint2*)((char*)Plds + byte) = pk;
    }
    bar_lds();  // P complete

    // ================= PV =================
    s8v pa[4];
#pragma unroll
    for (int mt = 0; mt < 4; ++mt) {
      int mm = 16 * mt + c;
      int byte = (mm * 64 + 16 * g) ^ ((mm & 6) << 3);
      pa[mt] = *(const s8v*)((const char*)Plds + byte);
    }
#pragma unroll
    for (int nt = 0; nt < 8; ++nt)
#pragma unroll
      for (int mt = 0; mt < 4; ++mt)
        acc[mt][nt] = __builtin_amdgcn_mfma_f32_16x16x32_bf16(pa[mt], etf[nt], acc[mt][nt], 0, 0, 0);
    // next tile's Sred writes are fenced by the barriers above
  }

  // ---- finalize
  if (NSPLIT == 1) {
    if (w < 4 && g == 0) l_lds[16 * w + c] = lcur;
    __syncthreads();
#pragma unroll
    for (int mt = 0; mt < 4; ++mt)
#pragma unroll
      for (int nt = 0; nt < 8; ++nt)
#pragma unroll
        for (int r = 0; r < 4; ++r) {
          size_t o = (size_t)(row0 + 16 * mt + 4 * g + r) * D_DIM + db + 16 * nt + c;
          out[o] = acc[mt][nt][r] * (1.f / l_lds[16 * mt + 4 * g + r]) + qg[o];
        }
  } else {
    u16* pc = pctx + (size_t)sp * NROWSZ * D_DIM;
#pragma unroll
    for (int mt = 0; mt < 4; ++mt)
#pragma unroll
      for (int nt = 0; nt < 8; ++nt)
#pragma unroll
        for (int r = 0; r < 4; ++r)
          pc[(size_t)(row0 + 16 * mt + 4 * g + r) * D_DIM + db + 16 * nt + c] =
              f2bf(acc[mt][nt][r]);
    if (w < 4 && g == 0)
      pstat[(size_t)sp * NROWSZ + row0 + 16 * w + c] = lcur;
  }
}

// ---------------------------------------------------------------------------
// Combine NSPLIT=4 partials: out = (sum ctx_sp) / (sum l_sp) + q
// ---------------------------------------------------------------------------
__global__ __launch_bounds__(256) void combine2_kernel(const float* __restrict__ qg,
                                                       const u16* __restrict__ pctx,
                                                       const float* __restrict__ pstat,
                                                       float* __restrict__ out) {
  const int r = blockIdx.x;
  const int t = threadIdx.x;
  float L = pstat[r] + pstat[NROWSZ + r] + pstat[2 * NROWSZ + r] + pstat[3 * NROWSZ + r];
  float inv = 1.f / L;
  size_t o = (size_t)r * D_DIM + t * 4;
  float sx = 0.f, sy = 0.f, sz = 0.f, sw = 0.f;
#pragma unroll
  for (int sp = 0; sp < 4; ++sp) {
    ushort4 u = *(const ushort4*)(pctx + (size_t)sp * NROWSZ * D_DIM + o);
    sx += bf2f(u.x); sy += bf2f(u.y); sz += bf2f(u.z); sw += bf2f(u.w);
  }
  float4 qv = *(const float4*)(qg + o);
  float4 res;
  res.x = sx * inv + qv.x;
  res.y = sy * inv + qv.y;
  res.z = sz * inv + qv.z;
  res.w = sw * inv + qv.w;
  *(float4*)(out + o) = res;
}

// ---------------------------------------------------------------------------
// Naive correctness fallback (tiny ws): one q-row per block.
// ---------------------------------------------------------------------------
__global__ __launch_bounds__(256) void naive_kernel(const float* __restrict__ qg,
                                                    const float* __restrict__ emb,
                                                    float* __restrict__ out) {
  __shared__ float s[VOCABSZ];
  __shared__ float qrow[D_DIM];
  __shared__ float lsh[4];
  const int r = blockIdx.x;
  const int t = threadIdx.x;
  for (int i = t; i < D_DIM; i += 256) qrow[i] = qg[(size_t)r * D_DIM + i];
  __syncthreads();
  float lpart = 0.f;
  for (int v = t; v < VOCABSZ; v += 256) {
    float dot = 0.f;
    for (int d = 0; d < D_DIM; d += 4) {
      float4 e = *(const float4*)(emb + (size_t)v * D_DIM + d);
      dot += qrow[d] * e.x + qrow[d + 1] * e.y + qrow[d + 2] * e.z + qrow[d + 3] * e.w;
    }
    float p = exp2f(dot * LOG2E);
    s[v] = p;
    lpart += p;
  }
  for (int o = 32; o; o >>= 1) lpart += __shfl_xor(lpart, o);
  if ((t & 63) == 0) lsh[t >> 6] = lpart;
  __syncthreads();
  float inv = 1.f / (lsh[0] + lsh[1] + lsh[2] + lsh[3]);
  float ax = 0.f, ay = 0.f, az = 0.f, aw = 0.f;
  for (int v = 0; v < VOCABSZ; ++v) {
    float p = s[v];
    float4 e = *(const float4*)(emb + (size_t)v * D_DIM + t * 4);
    ax += p * e.x; ay += p * e.y; az += p * e.z; aw += p * e.w;
  }
  size_t o = (size_t)r * D_DIM + t * 4;
  float4 qv = *(const float4*)(qg + o);
  float4 res;
  res.x = ax * inv + qv.x;
  res.y = ay * inv + qv.y;
  res.z = az * inv + qv.z;
  res.w = aw * inv + qv.w;
  *(float4*)(out + o) = res;
}

extern "C" void kernel_launch(void* const* d_in, const int* in_sizes, int n_in,
                              void* d_out, int out_size, void* d_ws, size_t ws_size,
                              hipStream_t stream) {
  const float* q = (const float*)d_in[0];
  const float* emb = (const float*)d_in[1];
  float* out = (float*)d_out;
  char* ws = (char*)d_ws;

  const size_t EBYTES = (size_t)VOCABSZ * D_DIM * 2;         // 65,536,000
  const size_t PCTX_BYTES = 4ull * NROWSZ * D_DIM * 2;       // 33,554,432 (bf16 x 4 splits)
  const size_t PSTAT_BYTES = 4ull * NROWSZ * 4;              // 65,536

  if (ws_size >= 2 * EBYTES + PCTX_BYTES + PSTAT_BYTES) {    // 164,691,968 (proven fits)
    u16* Ebf = (u16*)ws;
    u16* ETbf = (u16*)(ws + EBYTES);
    u16* pctx = (u16*)(ws + 2 * EBYTES);
    float* pstat = (float*)(ws + 2 * EBYTES + PCTX_BYTES);
    cvt_kernel<<<8000, 256, 0, stream>>>(emb, Ebf, ETbf);
    flash3_kernel<4><<<256, 512, 0, stream>>>(q, Ebf, ETbf, out, pctx, pstat);
    combine2_kernel<<<NROWSZ, 256, 0, stream>>>(q, pctx, pstat, out);
  } else if (ws_size >= 2 * EBYTES) {
    u16* Ebf = (u16*)ws;
    u16* ETbf = (u16*)(ws + EBYTES);
    cvt_kernel<<<8000, 256, 0, stream>>>(emb, Ebf, ETbf);
    flash3_kernel<1><<<NROWSZ / MBLK, 512, 0, stream>>>(q, Ebf, ETbf, out, nullptr, nullptr);
  } else {
    naive_kernel<<<NROWSZ, 256, 0, stream>>>(q, emb, out);
  }
}

// Round 4
// 1345.028 us; speedup vs baseline: 1.3304x; 1.3304x over previous
//
#include <hip/hip_runtime.h>
#include <hip/hip_bf16.h>

#define D_DIM 1024
#define VOCABSZ 32000
#define NROWSZ 4096
#define MBLK 64
#define LOG2E 1.44269504088896340736f

typedef unsigned short u16;
typedef short s8v __attribute__((ext_vector_type(8)));
typedef float f4v __attribute__((ext_vector_type(4)));

static __device__ __forceinline__ u16 f2bf(float f) {
  union { float f; unsigned int u; } x; x.f = f;
  unsigned int r = x.u + 0x7fffu + ((x.u >> 16) & 1u);
  return (u16)(r >> 16);
}
static __device__ __forceinline__ unsigned int pack2(float lo, float hi) {
  return (unsigned int)f2bf(lo) | ((unsigned int)f2bf(hi) << 16);
}
static __device__ __forceinline__ float bf2f(u16 b) {
  union { unsigned int u; float f; } x; x.u = ((unsigned int)b) << 16;
  return x.f;
}
static __device__ __forceinline__ float bfu_lo(unsigned int u) {
  union { unsigned int u; float f; } x; x.u = u << 16; return x.f;
}
static __device__ __forceinline__ float bfu_hi(unsigned int u) {
  union { unsigned int u; float f; } x; x.u = u & 0xffff0000u; return x.f;
}
static __device__ __forceinline__ f4v MFMA(s8v a, s8v b, f4v c) {
  return __builtin_amdgcn_mfma_f32_16x16x32_bf16(a, b, c, 0, 0, 0);
}
// LDS-only barrier: does NOT drain vmcnt -> global/DMA prefetches stay in flight.
static __device__ __forceinline__ void bar_lds() {
  asm volatile("s_waitcnt lgkmcnt(0)" ::: "memory");
  __builtin_amdgcn_s_barrier();
}
#define VM_WAIT(N) asm volatile("s_waitcnt vmcnt(" #N ")" ::: "memory")

#define GLOAD_LDS16(gp, lp)                                                        \
  __builtin_amdgcn_global_load_lds(                                               \
      (const __attribute__((address_space(1))) void*)(gp),                        \
      (__attribute__((address_space(3))) void*)(lp), 16, 0, 0)

// ---------------------------------------------------------------------------
// Prep: emb fp32 -> Ebf (plain bf16 [V][D]) and ETt (tiled transposed bf16:
// per 16-vocab tile gt, 32 KB chunk that is the exact LDS image [1024 d][16 v]).
// grid = 2000 blocks x 256 thr.
// ---------------------------------------------------------------------------
__global__ __launch_bounds__(256) void cvt2_kernel(const float* __restrict__ emb,
                                                   u16* __restrict__ Ebf,
                                                   u16* __restrict__ ETt) {
  __shared__ u16 T[16 * 1024];  // 32 KB
  const int b = blockIdx.x;
  const int t = threadIdx.x;
  const int v0 = b * 16;
#pragma unroll
  for (int k = 0; k < 16; ++k) {
    int ci = t + 256 * k;          // 0..4095
    int r = ci >> 8;               // 0..15
    int dq = (ci & 255) << 2;      // 0..1020
    float4 f = *(const float4*)(emb + (size_t)(v0 + r) * D_DIM + dq);
    ushort4 u;
    u.x = f2bf(f.x); u.y = f2bf(f.y); u.z = f2bf(f.z); u.w = f2bf(f.w);
    *(ushort4*)(T + r * 1024 + dq) = u;
  }
  __syncthreads();
  // Ebf plain rows
#pragma unroll
  for (int k = 0; k < 8; ++k) {
    int o = t + 256 * k;           // 0..2047 granules of 16B
    int v = o >> 7;
    int dq = (o & 127) << 3;
    uint4 x = *(const uint4*)(T + v * 1024 + dq);
    *(uint4*)(Ebf + (size_t)(v0 + v) * D_DIM + dq) = x;
  }
  // ETt tile image: byte(d, v) = d*32 + v*2
#pragma unroll
  for (int k = 0; k < 8; ++k) {
    int o = t + 256 * k;           // 0..2047
    int d = o >> 1;
    int h = (o & 1) << 3;          // v base 0 or 8
    uint4 x;
    x.x = (unsigned)T[(h + 0) * 1024 + d] | ((unsigned)T[(h + 1) * 1024 + d] << 16);
    x.y = (unsigned)T[(h + 2) * 1024 + d] | ((unsigned)T[(h + 3) * 1024 + d] << 16);
    x.z = (unsigned)T[(h + 4) * 1024 + d] | ((unsigned)T[(h + 5) * 1024 + d] << 16);
    x.w = (unsigned)T[(h + 6) * 1024 + d] | ((unsigned)T[(h + 7) * 1024 + d] << 16);
    *(uint4*)(ETt + (size_t)b * 16384 + (size_t)o * 8) = x;
  }
}

// ---------------------------------------------------------------------------
// Flash v4: 8 waves x 128-d slices, MBLK=64 rows, KV=16 tiles, pair-PV (K=32).
// ET staged via global_load_lds into 4-deep LDS ring (2 tiles ahead, counted
// vmcnt). E fragments register-prefetched 1 tile ahead (efA/efB ping-pong).
// No-max softmax (|S| bounded), duplicated across wave pairs. 2 barriers/tile.
// ---------------------------------------------------------------------------
template <int NSPLIT>
__global__ __launch_bounds__(512, 2) void flash4_kernel(
    const float* __restrict__ qg, const u16* __restrict__ Ebf,
    const u16* __restrict__ ETt, float* __restrict__ out,
    u16* __restrict__ pctx, float* __restrict__ pstat) {
  __shared__ char ETb[4 * 32768];     // 128 KB: ET tile ring, [1024 d][16 v] bf16 each
  __shared__ uint2 Sred[8][4][64];    // 16 KB: bf16x4-packed S^T partials
  __shared__ u16 Plds[MBLK * 32];     // 4 KB: [m][32 v], byte ^= (m&6)<<3
  __shared__ float l_lds[MBLK];

  const int tid = threadIdx.x;
  const int w = tid >> 6;
  const int l = tid & 63;
  const int g = l >> 4;
  const int c = l & 15;
  const int mtw = w & 3;
  const int bid = blockIdx.x;
  const int sp = (NSPLIT == 4) ? (bid & 3) : 0;
  const int rb = (NSPLIT == 4) ? (bid >> 2) : bid;
  const int row0 = rb * MBLK;
  const int db = w * 128;
  const int vslice = VOCABSZ / NSPLIT;
  const int ntiles = vslice / 16;      // 500 (NSPLIT=4) or 2000
  const int gt0 = (sp * vslice) >> 4;  // global tile base

  const f4v fzero = {0.f, 0.f, 0.f, 0.f};

  // ---- Q fragments (B-role): qf[mt][kt] = Q[row0+16mt+c][db+32kt+8g+i]
  s8v qf[4][4];
#pragma unroll
  for (int mt = 0; mt < 4; ++mt)
#pragma unroll
    for (int kt = 0; kt < 4; ++kt) {
      const float* src = qg + (size_t)(row0 + 16 * mt + c) * D_DIM + db + 32 * kt + 8 * g;
      float4 a = *(const float4*)src;
      float4 b = *(const float4*)(src + 4);
      s8v v;
      v[0] = (short)f2bf(a.x); v[1] = (short)f2bf(a.y);
      v[2] = (short)f2bf(a.z); v[3] = (short)f2bf(a.w);
      v[4] = (short)f2bf(b.x); v[5] = (short)f2bf(b.y);
      v[6] = (short)f2bf(b.z); v[7] = (short)f2bf(b.w);
      qf[mt][kt] = v;
    }

  f4v acc[4][8];
#pragma unroll
  for (int mt = 0; mt < 4; ++mt)
#pragma unroll
    for (int nt = 0; nt < 8; ++nt) acc[mt][nt] = fzero;

  float lcur = 0.f;

#define STAGE(U)                                                            \
  {                                                                         \
    const char* _gs = (const char*)ETt + ((size_t)(gt0 + (U)) << 15) + tid * 16; \
    char* _ls = ETb + (((U) & 3) << 15) + w * 1024;                         \
    GLOAD_LDS16(_gs, _ls);                                                  \
    GLOAD_LDS16(_gs + 8192, _ls + 8192);                                    \
    GLOAD_LDS16(_gs + 16384, _ls + 16384);                                  \
    GLOAD_LDS16(_gs + 24576, _ls + 24576);                                  \
  }

#define EF_LOAD(D0, D1, D2, D3, U)                                          \
  {                                                                         \
    const u16* _e = Ebf + ((size_t)((gt0 + (U)) * 16 + c)) * D_DIM + db + 8 * g; \
    D0 = *(const s8v*)_e;                                                   \
    D1 = *(const s8v*)(_e + 32);                                            \
    D2 = *(const s8v*)(_e + 64);                                            \
    D3 = *(const s8v*)(_e + 96);                                            \
  }

#define QK_STEP(E0, E1, E2, E3)                                             \
  {                                                                         \
    f4v st0 = fzero, st1 = fzero, st2 = fzero, st3 = fzero;                 \
    st0 = MFMA(E0, qf[0][0], st0); st1 = MFMA(E0, qf[1][0], st1);           \
    st2 = MFMA(E0, qf[2][0], st2); st3 = MFMA(E0, qf[3][0], st3);           \
    st0 = MFMA(E1, qf[0][1], st0); st1 = MFMA(E1, qf[1][1], st1);           \
    st2 = MFMA(E1, qf[2][1], st2); st3 = MFMA(E1, qf[3][1], st3);           \
    st0 = MFMA(E2, qf[0][2], st0); st1 = MFMA(E2, qf[1][2], st1);           \
    st2 = MFMA(E2, qf[2][2], st2); st3 = MFMA(E2, qf[3][2], st3);           \
    st0 = MFMA(E3, qf[0][3], st0); st1 = MFMA(E3, qf[1][3], st1);           \
    st2 = MFMA(E3, qf[2][3], st2); st3 = MFMA(E3, qf[3][3], st3);           \
    uint2 _pk;                                                              \
    _pk.x = pack2(st0[0], st0[1]); _pk.y = pack2(st0[2], st0[3]);           \
    Sred[w][0][l] = _pk;                                                    \
    _pk.x = pack2(st1[0], st1[1]); _pk.y = pack2(st1[2], st1[3]);           \
    Sred[w][1][l] = _pk;                                                    \
    _pk.x = pack2(st2[0], st2[1]); _pk.y = pack2(st2[2], st2[3]);           \
    Sred[w][2][l] = _pk;                                                    \
    _pk.x = pack2(st3[0], st3[1]); _pk.y = pack2(st3[2], st3[3]);           \
    Sred[w][3][l] = _pk;                                                    \
  }

#define SOFTMAX_HALF(VH)                                                    \
  {                                                                         \
    float s0 = 0.f, s1 = 0.f, s2 = 0.f, s3 = 0.f;                           \
    _Pragma("unroll") for (int ww = 0; ww < 8; ++ww) {                      \
      uint2 u = Sred[ww][mtw][l];                                           \
      s0 += bfu_lo(u.x); s1 += bfu_hi(u.x);                                 \
      s2 += bfu_lo(u.y); s3 += bfu_hi(u.y);                                 \
    }                                                                       \
    float p0 = exp2f(s0 * LOG2E), p1 = exp2f(s1 * LOG2E);                   \
    float p2 = exp2f(s2 * LOG2E), p3 = exp2f(s3 * LOG2E);                   \
    float lp = (p0 + p1) + (p2 + p3);                                       \
    lp += __shfl_xor(lp, 16);                                               \
    lp += __shfl_xor(lp, 32);                                               \
    lcur += lp;                                                             \
    if (w < 4) {                                                            \
      int m = 16 * mtw + c;                                                 \
      int byte = (m * 64 + ((VH) * 16 + 4 * g) * 2) ^ ((m & 6) << 3);       \
      uint2 pk;                                                             \
      pk.x = pack2(p0, p1); pk.y = pack2(p2, p3);                           \
      *(uint2*)((char*)Plds + byte) = pk;                                   \
    }                                                                       \
  }

#define PV_PAIR(TA, TB)                                                     \
  {                                                                         \
    s8v pa0, pa1, pa2, pa3;                                                 \
    { int mm = c;      pa0 = *(const s8v*)((const char*)Plds + ((mm * 64 + 16 * g) ^ ((mm & 6) << 3))); } \
    { int mm = 16 + c; pa1 = *(const s8v*)((const char*)Plds + ((mm * 64 + 16 * g) ^ ((mm & 6) << 3))); } \
    { int mm = 32 + c; pa2 = *(const s8v*)((const char*)Plds + ((mm * 64 + 16 * g) ^ ((mm & 6) << 3))); } \
    { int mm = 48 + c; pa3 = *(const s8v*)((const char*)Plds + ((mm * 64 + 16 * g) ^ ((mm & 6) << 3))); } \
    const char* _eb = ETb + (size_t)(((g < 2 ? (TA) : (TB)) & 3) << 15) +   \
                      (db + c) * 32 + (g & 1) * 16;                         \
    _Pragma("unroll") for (int nt = 0; nt < 8; ++nt) {                      \
      s8v ev = *(const s8v*)(_eb + nt * 512);                               \
      acc[0][nt] = MFMA(pa0, ev, acc[0][nt]);                               \
      acc[1][nt] = MFMA(pa1, ev, acc[1][nt]);                               \
      acc[2][nt] = MFMA(pa2, ev, acc[2][nt]);                               \
      acc[3][nt] = MFMA(pa3, ev, acc[3][nt]);                               \
    }                                                                       \
  }

  // ---- prologue: ef(0) to efA, stage tiles 0 and 1
  s8v efA0, efA1, efA2, efA3, efB0, efB1, efB2, efB3;
  EF_LOAD(efA0, efA1, efA2, efA3, 0);
  STAGE(0);
  STAGE(1);

  const int npairs = ntiles >> 1;
  for (int pt = 0; pt < npairs; ++pt) {
    const int t = pt << 1;
    // ================= tile t (even) =================
    EF_LOAD(efB0, efB1, efB2, efB3, t + 1);   // prefetch ef(t+1)
    VM_WAIT(16);                              // drain through stage(t-1): PV bufs ready
    bar_lds();                                // MB(t): stage(t-2..) landed for all waves
    if (pt > 0) { PV_PAIR(t - 2, t - 1); }    // LDS-only operands: overlaps in-flight loads
    QK_STEP(efA0, efA1, efA2, efA3);
    bar_lds();                                // B1(t): Sred visible, PV reads done
    if (t + 2 < ntiles) STAGE(t + 2);
    SOFTMAX_HALF(0);
    // ================= tile t+1 (odd) =================
    if (t + 2 < ntiles) { EF_LOAD(efA0, efA1, efA2, efA3, t + 2); }
    VM_WAIT(16);
    bar_lds();                                // MB(t+1)
    QK_STEP(efB0, efB1, efB2, efB3);
    bar_lds();                                // B1(t+1)
    if (t + 3 < ntiles) STAGE(t + 3);
    SOFTMAX_HALF(1);
  }
  // ---- epilogue PV for the last pair
  VM_WAIT(0);
  bar_lds();
  PV_PAIR(ntiles - 2, ntiles - 1);

  // ---- finalize
  if (NSPLIT == 1) {
    if (w < 4 && g == 0) l_lds[16 * mtw + c] = lcur;
    __syncthreads();
#pragma unroll
    for (int mt = 0; mt < 4; ++mt)
#pragma unroll
      for (int nt = 0; nt < 8; ++nt)
#pragma unroll
        for (int r = 0; r < 4; ++r) {
          size_t o = (size_t)(row0 + 16 * mt + 4 * g + r) * D_DIM + db + 16 * nt + c;
          out[o] = acc[mt][nt][r] * (1.f / l_lds[16 * mt + 4 * g + r]) + qg[o];
        }
  } else {
    u16* pc = pctx + (size_t)sp * NROWSZ * D_DIM;
#pragma unroll
    for (int mt = 0; mt < 4; ++mt)
#pragma unroll
      for (int nt = 0; nt < 8; ++nt)
#pragma unroll
        for (int r = 0; r < 4; ++r)
          pc[(size_t)(row0 + 16 * mt + 4 * g + r) * D_DIM + db + 16 * nt + c] =
              f2bf(acc[mt][nt][r]);
    if (w < 4 && g == 0)
      pstat[(size_t)sp * NROWSZ + row0 + 16 * mtw + c] = lcur;
  }
#undef STAGE
#undef EF_LOAD
#undef QK_STEP
#undef SOFTMAX_HALF
#undef PV_PAIR
}

// ---------------------------------------------------------------------------
// Combine NSPLIT=4 partials: out = (sum ctx_sp) / (sum l_sp) + q
// ---------------------------------------------------------------------------
__global__ __launch_bounds__(256) void combine2_kernel(const float* __restrict__ qg,
                                                       const u16* __restrict__ pctx,
                                                       const float* __restrict__ pstat,
                                                       float* __restrict__ out) {
  const int r = blockIdx.x;
  const int t = threadIdx.x;
  float L = pstat[r] + pstat[NROWSZ + r] + pstat[2 * NROWSZ + r] + pstat[3 * NROWSZ + r];
  float inv = 1.f / L;
  size_t o = (size_t)r * D_DIM + t * 4;
  float sx = 0.f, sy = 0.f, sz = 0.f, sw = 0.f;
#pragma unroll
  for (int sp = 0; sp < 4; ++sp) {
    ushort4 u = *(const ushort4*)(pctx + (size_t)sp * NROWSZ * D_DIM + o);
    sx += bf2f(u.x); sy += bf2f(u.y); sz += bf2f(u.z); sw += bf2f(u.w);
  }
  float4 qv = *(const float4*)(qg + o);
  float4 res;
  res.x = sx * inv + qv.x;
  res.y = sy * inv + qv.y;
  res.z = sz * inv + qv.z;
  res.w = sw * inv + qv.w;
  *(float4*)(out + o) = res;
}

// ---------------------------------------------------------------------------
// Naive correctness fallback (tiny ws): one q-row per block.
// ---------------------------------------------------------------------------
__global__ __launch_bounds__(256) void naive_kernel(const float* __restrict__ qg,
                                                    const float* __restrict__ emb,
                                                    float* __restrict__ out) {
  __shared__ float s[VOCABSZ];
  __shared__ float qrow[D_DIM];
  __shared__ float lsh[4];
  const int r = blockIdx.x;
  const int t = threadIdx.x;
  for (int i = t; i < D_DIM; i += 256) qrow[i] = qg[(size_t)r * D_DIM + i];
  __syncthreads();
  float lpart = 0.f;
  for (int v = t; v < VOCABSZ; v += 256) {
    float dot = 0.f;
    for (int d = 0; d < D_DIM; d += 4) {
      float4 e = *(const float4*)(emb + (size_t)v * D_DIM + d);
      dot += qrow[d] * e.x + qrow[d + 1] * e.y + qrow[d + 2] * e.z + qrow[d + 3] * e.w;
    }
    float p = exp2f(dot * LOG2E);
    s[v] = p;
    lpart += p;
  }
  for (int o = 32; o; o >>= 1) lpart += __shfl_xor(lpart, o);
  if ((t & 63) == 0) lsh[t >> 6] = lpart;
  __syncthreads();
  float inv = 1.f / (lsh[0] + lsh[1] + lsh[2] + lsh[3]);
  float ax = 0.f, ay = 0.f, az = 0.f, aw = 0.f;
  for (int v = 0; v < VOCABSZ; ++v) {
    float p = s[v];
    float4 e = *(const float4*)(emb + (size_t)v * D_DIM + t * 4);
    ax += p * e.x; ay += p * e.y; az += p * e.z; aw += p * e.w;
  }
  size_t o = (size_t)r * D_DIM + t * 4;
  float4 qv = *(const float4*)(qg + o);
  float4 res;
  res.x = ax * inv + qv.x;
  res.y = ay * inv + qv.y;
  res.z = az * inv + qv.z;
  res.w = aw * inv + qv.w;
  *(float4*)(out + o) = res;
}

extern "C" void kernel_launch(void* const* d_in, const int* in_sizes, int n_in,
                              void* d_out, int out_size, void* d_ws, size_t ws_size,
                              hipStream_t stream) {
  const float* q = (const float*)d_in[0];
  const float* emb = (const float*)d_in[1];
  float* out = (float*)d_out;
  char* ws = (char*)d_ws;

  const size_t EBYTES = (size_t)VOCABSZ * D_DIM * 2;         // 65,536,000
  const size_t PCTX_BYTES = 4ull * NROWSZ * D_DIM * 2;       // 33,554,432 (bf16 x 4 splits)
  const size_t PSTAT_BYTES = 4ull * NROWSZ * 4;              // 65,536

  if (ws_size >= 2 * EBYTES + PCTX_BYTES + PSTAT_BYTES) {    // 164,691,968 (proven fits)
    u16* Ebf = (u16*)ws;
    u16* ETt = (u16*)(ws + EBYTES);
    u16* pctx = (u16*)(ws + 2 * EBYTES);
    float* pstat = (float*)(ws + 2 * EBYTES + PCTX_BYTES);
    cvt2_kernel<<<VOCABSZ / 16, 256, 0, stream>>>(emb, Ebf, ETt);
    flash4_kernel<4><<<256, 512, 0, stream>>>(q, Ebf, ETt, out, pctx, pstat);
    combine2_kernel<<<NROWSZ, 256, 0, stream>>>(q, pctx, pstat, out);
  } else if (ws_size >= 2 * EBYTES) {
    u16* Ebf = (u16*)ws;
    u16* ETt = (u16*)(ws + EBYTES);
    cvt2_kernel<<<VOCABSZ / 16, 256, 0, stream>>>(emb, Ebf, ETt);
    flash4_kernel<1><<<NROWSZ / MBLK, 512, 0, stream>>>(q, Ebf, ETt, out, nullptr, nullptr);
  } else {
    naive_kernel<<<NROWSZ, 256, 0, stream>>>(q, emb, out);
  }
}

// Round 5
// 736.965 us; speedup vs baseline: 2.4281x; 1.8251x over previous
//
#include <hip/hip_runtime.h>
#include <hip/hip_bf16.h>

#define D_DIM 1024
#define VOCABSZ 32000
#define NROWSZ 4096
#define MBLK 64
#define LOG2E 1.44269504088896340736f

typedef unsigned short u16;
typedef short s8v __attribute__((ext_vector_type(8)));
typedef short s4v __attribute__((ext_vector_type(4)));
typedef float f4v __attribute__((ext_vector_type(4)));
typedef __attribute__((address_space(3))) const char* lds_p3;

static __device__ __forceinline__ u16 f2bf(float f) {
  union { float f; unsigned int u; } x; x.f = f;
  unsigned int r = x.u + 0x7fffu + ((x.u >> 16) & 1u);
  return (u16)(r >> 16);
}
static __device__ __forceinline__ unsigned int pack2(float lo, float hi) {
  return (unsigned int)f2bf(lo) | ((unsigned int)f2bf(hi) << 16);
}
static __device__ __forceinline__ float bf2f(u16 b) {
  union { unsigned int u; float f; } x; x.u = ((unsigned int)b) << 16;
  return x.f;
}
static __device__ __forceinline__ float bfu_lo(unsigned int u) {
  union { unsigned int u; float f; } x; x.u = u << 16; return x.f;
}
static __device__ __forceinline__ float bfu_hi(unsigned int u) {
  union { unsigned int u; float f; } x; x.u = u & 0xffff0000u; return x.f;
}
static __device__ __forceinline__ f4v MFMA(s8v a, s8v b, f4v c) {
  return __builtin_amdgcn_mfma_f32_16x16x32_bf16(a, b, c, 0, 0, 0);
}

#define GLOAD_LDS16(gp, lp)                                                  \
  __builtin_amdgcn_global_load_lds(                                         \
      (const __attribute__((address_space(1))) void*)(gp),                  \
      (__attribute__((address_space(3))) void*)(lp), 16, 0, 0)

// ---------------------------------------------------------------------------
// Prep: emb fp32 -> ETt: per 32-vocab tile, a 64 KB subtiled image:
//   byte(v,d) = ((v>>2)*64 + (d>>4))*128 + (v&3)*32 + (d&15)*2
// so QK A-frags are contiguous 16B rows and PV can use ds_read_b64_tr_b16.
// grid = 1000 blocks x 256 thr.
// ---------------------------------------------------------------------------
__global__ __launch_bounds__(256) void cvt3_kernel(const float* __restrict__ emb,
                                                   char* __restrict__ ETt) {
  const int b = blockIdx.x, t = threadIdx.x;
  const int v0 = b * 32;
  char* outp = ETt + ((size_t)b << 16);
#pragma unroll
  for (int k = 0; k < 16; ++k) {
    int ci = t + 256 * k;       // 0..4095
    int v = ci >> 7;            // 0..31
    int d8 = ci & 127;          // d = 8*d8
    const float* s = emb + (size_t)(v0 + v) * D_DIM + d8 * 8;
    float4 a = *(const float4*)s;
    float4 bb = *(const float4*)(s + 4);
    uint4 x;
    x.x = pack2(a.x, a.y); x.y = pack2(a.z, a.w);
    x.z = pack2(bb.x, bb.y); x.w = pack2(bb.z, bb.w);
    int off = ((v >> 2) * 64 + (d8 >> 1)) * 128 + (v & 3) * 32 + (d8 & 1) * 16;
    *(uint4*)(outp + off) = x;
  }
}

// ---------------------------------------------------------------------------
// Flash v5: 512 thr = 8 waves = 4 d-slices (256 d) x 2 m-halves (32 rows).
// KV=32 tile staged ONCE via global_load_lds (2-deep ring, subtiled image).
// QK A-frags: ds_read_b128 from tile; PV B-frags: ds_read_b64_tr_b16 from the
// SAME tile (no second global read). No-max softmax (|S| bounded ~60).
// 2 x __syncthreads per tile; stage(t+1) issued in the B1->B2 window.
// ---------------------------------------------------------------------------
template <int NSPLIT>
__global__ __launch_bounds__(512, 2) void flash5_kernel(
    const float* __restrict__ qg, const char* __restrict__ ETt,
    float* __restrict__ out, u16* __restrict__ pctx, float* __restrict__ pstat) {
  __shared__ char ring[2 * 65536];      // 128 KB: E-tile ring (subtiled image)
  __shared__ uint2 Sred[8 * 4 * 64];    // 16 KB: bf16x4 S^T partials [q][ds][l]
  __shared__ char Plds[4096];           // 4 KB: P [mh][32 m][32 v] bf16
  __shared__ float lred[8][16];

  const int tid = threadIdx.x;
  const int w = tid >> 6;
  const int l = tid & 63;
  const int g = l >> 4;
  const int c = l & 15;
  const int ds = w & 3;                 // d-slice: d in [ds*256, ds*256+256)
  const int mh = w >> 2;                // m-half: rows [mh*32, mh*32+32)
  const int bid = blockIdx.x;
  const int sp = (NSPLIT == 4) ? (bid & 3) : 0;
  const int rb = (NSPLIT == 4) ? (bid >> 2) : bid;
  const int row0 = rb * MBLK;
  const int vslice = VOCABSZ / NSPLIT;
  const int ntiles = vslice / 32;       // 250 or 1000
  const int gt0 = sp * ntiles;

  const f4v fzero = {0.f, 0.f, 0.f, 0.f};

  // ---- Q fragments (B-role): qf[mt][kt] = Q[row0+mh*32+16mt+c][ds*256+32kt+8g+i]
  s8v qf[2][8];
#pragma unroll
  for (int mt = 0; mt < 2; ++mt)
#pragma unroll
    for (int kt = 0; kt < 8; ++kt) {
      const float* src = qg + (size_t)(row0 + mh * 32 + 16 * mt + c) * D_DIM +
                         ds * 256 + 32 * kt + 8 * g;
      float4 a = *(const float4*)src;
      float4 b = *(const float4*)(src + 4);
      s8v v;
      v[0] = (short)f2bf(a.x); v[1] = (short)f2bf(a.y);
      v[2] = (short)f2bf(a.z); v[3] = (short)f2bf(a.w);
      v[4] = (short)f2bf(b.x); v[5] = (short)f2bf(b.y);
      v[6] = (short)f2bf(b.z); v[7] = (short)f2bf(b.w);
      qf[mt][kt] = v;
    }

  f4v acc[2][16];
#pragma unroll
  for (int mt = 0; mt < 2; ++mt)
#pragma unroll
    for (int nt = 0; nt < 16; ++nt) acc[mt][nt] = fzero;

  float lcur = 0.f;

#define STAGE(U)                                                             \
  {                                                                          \
    const char* _gs = ETt + (((size_t)(gt0 + (U))) << 16) + tid * 16;        \
    char* _ls = ring + (((U) & 1) << 16) + tid * 16;                         \
    _Pragma("unroll") for (int _j = 0; _j < 8; ++_j)                         \
        GLOAD_LDS16(_gs + _j * 8192, _ls + _j * 8192);                       \
  }

  // prologue: tile 0 staged and drained (syncthreads emits vmcnt(0))
  STAGE(0);
  __syncthreads();

  for (int t = 0; t < ntiles; ++t) {
    const char* buf = ring + ((t & 1) << 16);

    // ================= QK: S^T partial over this wave's 256-d slice =========
#pragma unroll
    for (int vt = 0; vt < 2; ++vt) {
      const char* bp = buf + (((4 * vt + (c >> 2)) * 64 + 16 * ds + (g >> 1)) * 128 +
                              (c & 3) * 32 + (g & 1) * 16);
      f4v st0 = fzero, st1 = fzero;
#pragma unroll
      for (int kt = 0; kt < 8; ++kt) {
        s8v ek = *(const s8v*)(bp + kt * 256);
        st0 = MFMA(ek, qf[0][kt], st0);
        st1 = MFMA(ek, qf[1][kt], st1);
      }
      int qb = ((mh * 4 + vt * 2) * 4 + ds) * 64 + l;
      uint2 pk;
      pk.x = pack2(st0[0], st0[1]); pk.y = pack2(st0[2], st0[3]);
      Sred[qb] = pk;
      pk.x = pack2(st1[0], st1[1]); pk.y = pack2(st1[2], st1[3]);
      Sred[qb + 256] = pk;             // mt=1 -> quadrant q+1
    }
    __syncthreads();                   // B1: Sred visible (no DMA in flight)

    // stage next tile: in flight across softmax, drained by B2's vmcnt(0)
    if (t + 1 < ntiles) STAGE(t + 1);

    // ================= softmax: wave (ds,mh) owns quadrant (vt=ds>>1, mt=ds&1, mh)
    {
      int qq = mh * 4 + ds;
      f4v ss = fzero;
#pragma unroll
      for (int ww = 0; ww < 4; ++ww) {
        uint2 u = Sred[(qq * 4 + ww) * 64 + l];
        ss[0] += bfu_lo(u.x); ss[1] += bfu_hi(u.x);
        ss[2] += bfu_lo(u.y); ss[3] += bfu_hi(u.y);
      }
      float p0 = exp2f(ss[0] * LOG2E), p1 = exp2f(ss[1] * LOG2E);
      float p2 = exp2f(ss[2] * LOG2E), p3 = exp2f(ss[3] * LOG2E);
      int pb = mh * 2048 + (16 * (ds & 1) + c) * 64 + (16 * (ds >> 1) + 4 * g) * 2;
      uint2 pw; pw.x = pack2(p0, p1); pw.y = pack2(p2, p3);
      *(uint2*)(Plds + pb) = pw;
      float lp = (p0 + p1) + (p2 + p3);
      lp += __shfl_xor(lp, 16);
      lp += __shfl_xor(lp, 32);
      lcur += lp;
    }
    __syncthreads();                   // B2: P visible + stage(t+1) drained

    // ================= PV: A = P rows (b128), B = E^T via tr-reads ==========
    {
      int pab = mh * 2048 + c * 64 + g * 16;
      s8v pa0 = *(const s8v*)(Plds + pab);
      s8v pa1 = *(const s8v*)(Plds + pab + 1024);
#pragma unroll
      for (int bb = 0; bb < 2; ++bb) {
        s4v trv[16];
#pragma unroll
        for (int k = 0; k < 8; ++k) {
          int nt = bb * 8 + k;
          const char* a0 = buf + ((2 * g) * 64 + 16 * ds + nt) * 128 + c * 2;
          asm volatile("ds_read_b64_tr_b16 %0, %1"
                       : "=v"(trv[2 * k]) : "v"((lds_p3)a0));
          asm volatile("ds_read_b64_tr_b16 %0, %1"
                       : "=v"(trv[2 * k + 1]) : "v"((lds_p3)(a0 + 8192)));
        }
        asm volatile("s_waitcnt lgkmcnt(0)" ::: "memory");
        __builtin_amdgcn_sched_barrier(0);
#pragma unroll
        for (int k = 0; k < 8; ++k) {
          int nt = bb * 8 + k;
          union { s4v s[2]; s8v v; } ev;
          ev.s[0] = trv[2 * k]; ev.s[1] = trv[2 * k + 1];
          acc[0][nt] = MFMA(pa0, ev.v, acc[0][nt]);
          acc[1][nt] = MFMA(pa1, ev.v, acc[1][nt]);
        }
      }
    }
  }
#undef STAGE

  // ---- finalize: l reduction across vt (ds pairs {mt, 2+mt})
  __syncthreads();
  if (g == 0) lred[mh * 4 + ds][c] = lcur;
  __syncthreads();

  if (NSPLIT == 1) {
#pragma unroll
    for (int mt = 0; mt < 2; ++mt) {
      float inv[4];
#pragma unroll
      for (int r = 0; r < 4; ++r)
        inv[r] = 1.f / (lred[mh * 4 + mt][4 * g + r] + lred[mh * 4 + 2 + mt][4 * g + r]);
#pragma unroll
      for (int nt = 0; nt < 16; ++nt)
#pragma unroll
        for (int r = 0; r < 4; ++r) {
          size_t o = (size_t)(row0 + mh * 32 + 16 * mt + 4 * g + r) * D_DIM +
                     ds * 256 + 16 * nt + c;
          out[o] = acc[mt][nt][r] * inv[r] + qg[o];
        }
    }
  } else {
    u16* pc = pctx + (size_t)sp * NROWSZ * D_DIM;
#pragma unroll
    for (int mt = 0; mt < 2; ++mt)
#pragma unroll
      for (int nt = 0; nt < 16; ++nt)
#pragma unroll
        for (int r = 0; r < 4; ++r)
          pc[(size_t)(row0 + mh * 32 + 16 * mt + 4 * g + r) * D_DIM +
             ds * 256 + 16 * nt + c] = f2bf(acc[mt][nt][r]);
    if (ds < 2 && g == 0)
      pstat[(size_t)sp * NROWSZ + row0 + mh * 32 + 16 * ds + c] =
          lred[mh * 4 + ds][c] + lred[mh * 4 + 2 + ds][c];
  }
}

// ---------------------------------------------------------------------------
// Combine NSPLIT=4 partials: out = (sum ctx_sp) / (sum l_sp) + q
// ---------------------------------------------------------------------------
__global__ __launch_bounds__(256) void combine2_kernel(const float* __restrict__ qg,
                                                       const u16* __restrict__ pctx,
                                                       const float* __restrict__ pstat,
                                                       float* __restrict__ out) {
  const int r = blockIdx.x;
  const int t = threadIdx.x;
  float L = pstat[r] + pstat[NROWSZ + r] + pstat[2 * NROWSZ + r] + pstat[3 * NROWSZ + r];
  float inv = 1.f / L;
  size_t o = (size_t)r * D_DIM + t * 4;
  float sx = 0.f, sy = 0.f, sz = 0.f, sw = 0.f;
#pragma unroll
  for (int sp = 0; sp < 4; ++sp) {
    ushort4 u = *(const ushort4*)(pctx + (size_t)sp * NROWSZ * D_DIM + o);
    sx += bf2f(u.x); sy += bf2f(u.y); sz += bf2f(u.z); sw += bf2f(u.w);
  }
  float4 qv = *(const float4*)(qg + o);
  float4 res;
  res.x = sx * inv + qv.x;
  res.y = sy * inv + qv.y;
  res.z = sz * inv + qv.z;
  res.w = sw * inv + qv.w;
  *(float4*)(out + o) = res;
}

// ---------------------------------------------------------------------------
// Naive correctness fallback (tiny ws): one q-row per block.
// ---------------------------------------------------------------------------
__global__ __launch_bounds__(256) void naive_kernel(const float* __restrict__ qg,
                                                    const float* __restrict__ emb,
                                                    float* __restrict__ out) {
  __shared__ float s[VOCABSZ];
  __shared__ float qrow[D_DIM];
  __shared__ float lsh[4];
  const int r = blockIdx.x;
  const int t = threadIdx.x;
  for (int i = t; i < D_DIM; i += 256) qrow[i] = qg[(size_t)r * D_DIM + i];
  __syncthreads();
  float lpart = 0.f;
  for (int v = t; v < VOCABSZ; v += 256) {
    float dot = 0.f;
    for (int d = 0; d < D_DIM; d += 4) {
      float4 e = *(const float4*)(emb + (size_t)v * D_DIM + d);
      dot += qrow[d] * e.x + qrow[d + 1] * e.y + qrow[d + 2] * e.z + qrow[d + 3] * e.w;
    }
    float p = exp2f(dot * LOG2E);
    s[v] = p;
    lpart += p;
  }
  for (int o = 32; o; o >>= 1) lpart += __shfl_xor(lpart, o);
  if ((t & 63) == 0) lsh[t >> 6] = lpart;
  __syncthreads();
  float inv = 1.f / (lsh[0] + lsh[1] + lsh[2] + lsh[3]);
  float ax = 0.f, ay = 0.f, az = 0.f, aw = 0.f;
  for (int v = 0; v < VOCABSZ; ++v) {
    float p = s[v];
    float4 e = *(const float4*)(emb + (size_t)v * D_DIM + t * 4);
    ax += p * e.x; ay += p * e.y; az += p * e.z; aw += p * e.w;
  }
  size_t o = (size_t)r * D_DIM + t * 4;
  float4 qv = *(const float4*)(qg + o);
  float4 res;
  res.x = ax * inv + qv.x;
  res.y = ay * inv + qv.y;
  res.z = az * inv + qv.z;
  res.w = aw * inv + qv.w;
  *(float4*)(out + o) = res;
}

extern "C" void kernel_launch(void* const* d_in, const int* in_sizes, int n_in,
                              void* d_out, int out_size, void* d_ws, size_t ws_size,
                              hipStream_t stream) {
  const float* q = (const float*)d_in[0];
  const float* emb = (const float*)d_in[1];
  float* out = (float*)d_out;
  char* ws = (char*)d_ws;

  const size_t ETT_BYTES = 65536000ull;                      // 1000 tiles x 64 KB
  const size_t PCTX_BYTES = 4ull * NROWSZ * D_DIM * 2;       // 33,554,432
  const size_t PSTAT_BYTES = 4ull * NROWSZ * 4;              // 65,536

  if (ws_size >= ETT_BYTES + PCTX_BYTES + PSTAT_BYTES) {     // 99,155,968 (fits proven ws)
    char* ETt = ws;
    u16* pctx = (u16*)(ws + ETT_BYTES);
    float* pstat = (float*)(ws + ETT_BYTES + PCTX_BYTES);
    cvt3_kernel<<<VOCABSZ / 32, 256, 0, stream>>>(emb, ETt);
    flash5_kernel<4><<<256, 512, 0, stream>>>(q, ETt, out, pctx, pstat);
    combine2_kernel<<<NROWSZ, 256, 0, stream>>>(q, pctx, pstat, out);
  } else if (ws_size >= ETT_BYTES) {
    char* ETt = ws;
    cvt3_kernel<<<VOCABSZ / 32, 256, 0, stream>>>(emb, ETt);
    flash5_kernel<1><<<NROWSZ / MBLK, 512, 0, stream>>>(q, ETt, out, nullptr, nullptr);
  } else {
    naive_kernel<<<NROWSZ, 256, 0, stream>>>(q, emb, out);
  }
}

// Round 8
// 614.665 us; speedup vs baseline: 2.9112x; 1.1990x over previous
//
#include <hip/hip_runtime.h>
#include <hip/hip_bf16.h>

#define D_DIM 1024
#define VOCABSZ 32000
#define NROWSZ 4096
#define MBLK 64
#define LOG2E 1.44269504088896340736f

typedef unsigned short u16;
typedef short s8v __attribute__((ext_vector_type(8)));
typedef short s4v __attribute__((ext_vector_type(4)));
typedef float f4v __attribute__((ext_vector_type(4)));
typedef __attribute__((address_space(3))) const char* lds_p3;

static __device__ __forceinline__ u16 f2bf(float f) {
  union { float f; unsigned int u; } x; x.f = f;
  unsigned int r = x.u + 0x7fffu + ((x.u >> 16) & 1u);
  return (u16)(r >> 16);
}
static __device__ __forceinline__ unsigned int pack2(float lo, float hi) {
  return (unsigned int)f2bf(lo) | ((unsigned int)f2bf(hi) << 16);
}
static __device__ __forceinline__ float bf2f(u16 b) {
  union { unsigned int u; float f; } x; x.u = ((unsigned int)b) << 16;
  return x.f;
}
static __device__ __forceinline__ float bfu_lo(unsigned int u) {
  union { unsigned int u; float f; } x; x.u = u << 16; return x.f;
}
static __device__ __forceinline__ float bfu_hi(unsigned int u) {
  union { unsigned int u; float f; } x; x.u = u & 0xffff0000u; return x.f;
}
static __device__ __forceinline__ f4v MFMA(s8v a, s8v b, f4v c) {
  return __builtin_amdgcn_mfma_f32_16x16x32_bf16(a, b, c, 0, 0, 0);
}

#define GLOAD_LDS16(gp, lp)                                                  \
  __builtin_amdgcn_global_load_lds(                                         \
      (const __attribute__((address_space(1))) void*)(gp),                  \
      (__attribute__((address_space(3))) void*)(lp), 16, 0, 0)

// ---------------------------------------------------------------------------
// Prep: emb fp32 -> ETt: per 32-vocab tile, a 64 KB subtiled image:
//   byte(v,d) = ((v>>2)*64 + (d>>4))*128 + (v&3)*32 + (d&15)*2
// QK A-frags = contiguous 16B rows; PV B-frags via ds_read_b64_tr_b16.
// ---------------------------------------------------------------------------
__global__ __launch_bounds__(256) void cvt3_kernel(const float* __restrict__ emb,
                                                   char* __restrict__ ETt) {
  const int b = blockIdx.x, t = threadIdx.x;
  const int v0 = b * 32;
  char* outp = ETt + ((size_t)b << 16);
#pragma unroll
  for (int k = 0; k < 16; ++k) {
    int ci = t + 256 * k;       // 0..4095
    int v = ci >> 7;            // 0..31
    int d8 = ci & 127;          // d = 8*d8
    const float* s = emb + (size_t)(v0 + v) * D_DIM + d8 * 8;
    float4 a = *(const float4*)s;
    float4 bb = *(const float4*)(s + 4);
    uint4 x;
    x.x = pack2(a.x, a.y); x.y = pack2(a.z, a.w);
    x.z = pack2(bb.x, bb.y); x.w = pack2(bb.z, bb.w);
    int off = ((v >> 2) * 64 + (d8 >> 1)) * 128 + (v & 3) * 32 + (d8 & 1) * 16;
    *(uint4*)(outp + off) = x;
  }
}

// ---------------------------------------------------------------------------
// Flash v8: EXACT v5 structure/barriers (proven 737us) with three deltas:
//  (1) STAGE(t+1) issued after B2 (was after B1) -> DMA flight covered by the
//      whole PV phase, drained by next tile's B1 implicit vmcnt(0).
//  (2) LOG2E folded into Q fragments (exp2 direct in softmax).
//  (3) row-sum shfl deferred to epilogue (linear).
// 512 thr = 8 waves = 4 d-slices x 2 m-halves. KV=32 per tile.
// ---------------------------------------------------------------------------
template <int NSPLIT>
__global__ __launch_bounds__(512, 2) void flash8_kernel(
    const float* __restrict__ qg, const char* __restrict__ ETt,
    float* __restrict__ out, u16* __restrict__ pctx, float* __restrict__ pstat) {
  __shared__ char ring[2 * 65536];      // 128 KB: E-tile ring (subtiled image)
  __shared__ uint2 Sred[8 * 4 * 64];    // 16 KB: bf16x4 S^T partials
  __shared__ char Plds[4096];           // 4 KB: P [mh][32 m][32 v] bf16
  __shared__ float lred[8][16];

  const int tid = threadIdx.x;
  const int w = tid >> 6;
  const int l = tid & 63;
  const int g = l >> 4;
  const int c = l & 15;
  const int ds = w & 3;                 // d-slice: [ds*256, ds*256+256)
  const int mh = w >> 2;                // m-half: rows [mh*32, mh*32+32)
  const int bid = blockIdx.x;
  const int sp = (NSPLIT == 4) ? (bid & 3) : 0;
  const int rb = (NSPLIT == 4) ? (bid >> 2) : bid;
  const int row0 = rb * MBLK;
  const int vslice = VOCABSZ / NSPLIT;
  const int ntiles = vslice / 32;       // 250 or 1000
  const int gt0 = sp * ntiles;

  const f4v fzero = {0.f, 0.f, 0.f, 0.f};

  // ---- Q fragments (B-role), pre-scaled by LOG2E so softmax is exp2-direct.
  s8v qf[2][8];
#pragma unroll
  for (int mt = 0; mt < 2; ++mt)
#pragma unroll
    for (int kt = 0; kt < 8; ++kt) {
      const float* src = qg + (size_t)(row0 + mh * 32 + 16 * mt + c) * D_DIM +
                         ds * 256 + 32 * kt + 8 * g;
      float4 a = *(const float4*)src;
      float4 b = *(const float4*)(src + 4);
      s8v v;
      v[0] = (short)f2bf(a.x * LOG2E); v[1] = (short)f2bf(a.y * LOG2E);
      v[2] = (short)f2bf(a.z * LOG2E); v[3] = (short)f2bf(a.w * LOG2E);
      v[4] = (short)f2bf(b.x * LOG2E); v[5] = (short)f2bf(b.y * LOG2E);
      v[6] = (short)f2bf(b.z * LOG2E); v[7] = (short)f2bf(b.w * LOG2E);
      qf[mt][kt] = v;
    }

  f4v acc[2][16];
#pragma unroll
  for (int mt = 0; mt < 2; ++mt)
#pragma unroll
    for (int nt = 0; nt < 16; ++nt) acc[mt][nt] = fzero;

  float lcur = 0.f;

#define STAGE(U)                                                             \
  {                                                                          \
    const char* _gs = ETt + (((size_t)(gt0 + (U))) << 16) + tid * 16;        \
    char* _ls = ring + (((U) & 1) << 16) + tid * 16;                         \
    _Pragma("unroll") for (int _j = 0; _j < 8; ++_j)                         \
        GLOAD_LDS16(_gs + _j * 8192, _ls + _j * 8192);                       \
  }

  // prologue: tile 0 staged and drained (syncthreads emits vmcnt(0))
  STAGE(0);
  __syncthreads();

  for (int t = 0; t < ntiles; ++t) {
    const char* buf = ring + ((t & 1) << 16);

    // ================= QK: S^T partial over this wave's 256-d slice =========
#pragma unroll
    for (int vt = 0; vt < 2; ++vt) {
      const char* bp = buf + (((4 * vt + (c >> 2)) * 64 + 16 * ds + (g >> 1)) * 128 +
                              (c & 3) * 32 + (g & 1) * 16);
      f4v st0 = fzero, st1 = fzero;
#pragma unroll
      for (int kt = 0; kt < 8; ++kt) {
        s8v ek = *(const s8v*)(bp + kt * 256);
        st0 = MFMA(ek, qf[0][kt], st0);
        st1 = MFMA(ek, qf[1][kt], st1);
      }
      int qb = ((mh * 4 + vt * 2) * 4 + ds) * 64 + l;
      uint2 pk;
      pk.x = pack2(st0[0], st0[1]); pk.y = pack2(st0[2], st0[3]);
      Sred[qb] = pk;
      pk.x = pack2(st1[0], st1[1]); pk.y = pack2(st1[2], st1[3]);
      Sred[qb + 256] = pk;             // mt=1 -> quadrant q+1
    }
    __syncthreads();                   // B1: Sred visible; drains prior STAGE DMA
                                       // (issued a full PV-phase ago -> hidden)

    // ================= softmax: wave (ds,mh) owns quadrant =================
    {
      int qq = mh * 4 + ds;
      f4v ss = fzero;
#pragma unroll
      for (int ww = 0; ww < 4; ++ww) {
        uint2 u = Sred[(qq * 4 + ww) * 64 + l];
        ss[0] += bfu_lo(u.x); ss[1] += bfu_hi(u.x);
        ss[2] += bfu_lo(u.y); ss[3] += bfu_hi(u.y);
      }
      float p0 = exp2f(ss[0]), p1 = exp2f(ss[1]);
      float p2 = exp2f(ss[2]), p3 = exp2f(ss[3]);
      int pb = mh * 2048 + (16 * (ds & 1) + c) * 64 + (16 * (ds >> 1) + 4 * g) * 2;
      uint2 pw; pw.x = pack2(p0, p1); pw.y = pack2(p2, p3);
      *(uint2*)(Plds + pb) = pw;
      lcur += (p0 + p1) + (p2 + p3);   // row-sum shfl deferred to epilogue
    }
    __syncthreads();                   // B2: P visible (no DMA in flight here)

    // stage next tile: in flight across PV + next QK, drained at next B1
    if (t + 1 < ntiles) STAGE(t + 1);

    // ================= PV: A = P rows (b128), B = E^T via tr-reads ==========
    {
      int pab = mh * 2048 + c * 64 + g * 16;
      s8v pa0 = *(const s8v*)(Plds + pab);
      s8v pa1 = *(const s8v*)(Plds + pab + 1024);
#pragma unroll
      for (int bb = 0; bb < 2; ++bb) {
        s4v trv[16];
#pragma unroll
        for (int k = 0; k < 8; ++k) {
          int nt = bb * 8 + k;
          const char* a0 = buf + ((2 * g) * 64 + 16 * ds + nt) * 128 + c * 2;
          asm volatile("ds_read_b64_tr_b16 %0, %1"
                       : "=v"(trv[2 * k]) : "v"((lds_p3)a0));
          asm volatile("ds_read_b64_tr_b16 %0, %1"
                       : "=v"(trv[2 * k + 1]) : "v"((lds_p3)(a0 + 8192)));
        }
        asm volatile("s_waitcnt lgkmcnt(0)" ::: "memory");
        __builtin_amdgcn_sched_barrier(0);
#pragma unroll
        for (int k = 0; k < 8; ++k) {
          int nt = bb * 8 + k;
          union { s4v s[2]; s8v v; } ev;
          ev.s[0] = trv[2 * k]; ev.s[1] = trv[2 * k + 1];
          acc[0][nt] = MFMA(pa0, ev.v, acc[0][nt]);
          acc[1][nt] = MFMA(pa1, ev.v, acc[1][nt]);
        }
      }
    }
  }
#undef STAGE

  // ---- finalize: deferred row-sum reduction, then normalize+write
  {
    float lp = lcur;
    lp += __shfl_xor(lp, 16);
    lp += __shfl_xor(lp, 32);
    __syncthreads();
    if (g == 0) lred[mh * 4 + ds][c] = lp;
  }
  __syncthreads();

  if (NSPLIT == 1) {
#pragma unroll
    for (int mt = 0; mt < 2; ++mt) {
      float inv[4];
#pragma unroll
      for (int r = 0; r < 4; ++r)
        inv[r] = 1.f / (lred[mh * 4 + mt][4 * g + r] + lred[mh * 4 + 2 + mt][4 * g + r]);
#pragma unroll
      for (int nt = 0; nt < 16; ++nt)
#pragma unroll
        for (int r = 0; r < 4; ++r) {
          size_t o = (size_t)(row0 + mh * 32 + 16 * mt + 4 * g + r) * D_DIM +
                     ds * 256 + 16 * nt + c;
          out[o] = acc[mt][nt][r] * inv[r] + qg[o];
        }
    }
  } else {
    u16* pc = pctx + (size_t)sp * NROWSZ * D_DIM;
#pragma unroll
    for (int mt = 0; mt < 2; ++mt)
#pragma unroll
      for (int nt = 0; nt < 16; ++nt)
#pragma unroll
        for (int r = 0; r < 4; ++r)
          pc[(size_t)(row0 + mh * 32 + 16 * mt + 4 * g + r) * D_DIM +
             ds * 256 + 16 * nt + c] = f2bf(acc[mt][nt][r]);
    if (ds < 2 && g == 0)
      pstat[(size_t)sp * NROWSZ + row0 + mh * 32 + 16 * ds + c] =
          lred[mh * 4 + ds][c] + lred[mh * 4 + 2 + ds][c];
  }
}

// ---------------------------------------------------------------------------
// Combine NSPLIT=4 partials: out = (sum ctx_sp) / (sum l_sp) + q
// ---------------------------------------------------------------------------
__global__ __launch_bounds__(256) void combine2_kernel(const float* __restrict__ qg,
                                                       const u16* __restrict__ pctx,
                                                       const float* __restrict__ pstat,
                                                       float* __restrict__ out) {
  const int r = blockIdx.x;
  const int t = threadIdx.x;
  float L = pstat[r] + pstat[NROWSZ + r] + pstat[2 * NROWSZ + r] + pstat[3 * NROWSZ + r];
  float inv = 1.f / L;
  size_t o = (size_t)r * D_DIM + t * 4;
  float sx = 0.f, sy = 0.f, sz = 0.f, sw = 0.f;
#pragma unroll
  for (int sp = 0; sp < 4; ++sp) {
    ushort4 u = *(const ushort4*)(pctx + (size_t)sp * NROWSZ * D_DIM + o);
    sx += bf2f(u.x); sy += bf2f(u.y); sz += bf2f(u.z); sw += bf2f(u.w);
  }
  float4 qv = *(const float4*)(qg + o);
  float4 res;
  res.x = sx * inv + qv.x;
  res.y = sy * inv + qv.y;
  res.z = sz * inv + qv.z;
  res.w = sw * inv + qv.w;
  *(float4*)(out + o) = res;
}

// ---------------------------------------------------------------------------
// Naive correctness fallback (tiny ws): one q-row per block.
// ---------------------------------------------------------------------------
__global__ __launch_bounds__(256) void naive_kernel(const float* __restrict__ qg,
                                                    const float* __restrict__ emb,
                                                    float* __restrict__ out) {
  __shared__ float s[VOCABSZ];
  __shared__ float qrow[D_DIM];
  __shared__ float lsh[4];
  const int r = blockIdx.x;
  const int t = threadIdx.x;
  for (int i = t; i < D_DIM; i += 256) qrow[i] = qg[(size_t)r * D_DIM + i];
  __syncthreads();
  float lpart = 0.f;
  for (int v = t; v < VOCABSZ; v += 256) {
    float dot = 0.f;
    for (int d = 0; d < D_DIM; d += 4) {
      float4 e = *(const float4*)(emb + (size_t)v * D_DIM + d);
      dot += qrow[d] * e.x + qrow[d + 1] * e.y + qrow[d + 2] * e.z + qrow[d + 3] * e.w;
    }
    float p = exp2f(dot * LOG2E);
    s[v] = p;
    lpart += p;
  }
  for (int o = 32; o; o >>= 1) lpart += __shfl_xor(lpart, o);
  if ((t & 63) == 0) lsh[t >> 6] = lpart;
  __syncthreads();
  float inv = 1.f / (lsh[0] + lsh[1] + lsh[2] + lsh[3]);
  float ax = 0.f, ay = 0.f, az = 0.f, aw = 0.f;
  for (int v = 0; v < VOCABSZ; ++v) {
    float p = s[v];
    float4 e = *(const float4*)(emb + (size_t)v * D_DIM + t * 4);
    ax += p * e.x; ay += p * e.y; az += p * e.z; aw += p * e.w;
  }
  size_t o = (size_t)r * D_DIM + t * 4;
  float4 qv = *(const float4*)(qg + o);
  float4 res;
  res.x = ax * inv + qv.x;
  res.y = ay * inv + qv.y;
  res.z = az * inv + qv.z;
  res.w = aw * inv + qv.w;
  *(float4*)(out + o) = res;
}

extern "C" void kernel_launch(void* const* d_in, const int* in_sizes, int n_in,
                              void* d_out, int out_size, void* d_ws, size_t ws_size,
                              hipStream_t stream) {
  const float* q = (const float*)d_in[0];
  const float* emb = (const float*)d_in[1];
  float* out = (float*)d_out;
  char* ws = (char*)d_ws;

  const size_t ETT_BYTES = 65536000ull;                      // 1000 tiles x 64 KB
  const size_t PCTX_BYTES = 4ull * NROWSZ * D_DIM * 2;       // 33,554,432
  const size_t PSTAT_BYTES = 4ull * NROWSZ * 4;              // 65,536

  if (ws_size >= ETT_BYTES + PCTX_BYTES + PSTAT_BYTES) {     // 99,155,968
    char* ETt = ws;
    u16* pctx = (u16*)(ws + ETT_BYTES);
    float* pstat = (float*)(ws + ETT_BYTES + PCTX_BYTES);
    cvt3_kernel<<<VOCABSZ / 32, 256, 0, stream>>>(emb, ETt);
    flash8_kernel<4><<<256, 512, 0, stream>>>(q, ETt, out, pctx, pstat);
    combine2_kernel<<<NROWSZ, 256, 0, stream>>>(q, pctx, pstat, out);
  } else if (ws_size >= ETT_BYTES) {
    char* ETt = ws;
    cvt3_kernel<<<VOCABSZ / 32, 256, 0, stream>>>(emb, ETt);
    flash8_kernel<1><<<NROWSZ / MBLK, 512, 0, stream>>>(q, ETt, out, nullptr, nullptr);
  } else {
    naive_kernel<<<NROWSZ, 256, 0, stream>>>(q, emb, out);
  }
}

// Round 9
// 590.967 us; speedup vs baseline: 3.0280x; 1.0401x over previous
//
#include <hip/hip_runtime.h>
#include <hip/hip_bf16.h>

#define D_DIM 1024
#define VOCABSZ 32000
#define NROWSZ 4096
#define MBLK 64
#define LOG2E 1.44269504088896340736f

typedef unsigned short u16;
typedef short s8v __attribute__((ext_vector_type(8)));
typedef short s4v __attribute__((ext_vector_type(4)));
typedef float f4v __attribute__((ext_vector_type(4)));
typedef __attribute__((address_space(3))) const char* lds_p3;

static __device__ __forceinline__ u16 f2bf(float f) {
  union { float f; unsigned int u; } x; x.f = f;
  unsigned int r = x.u + 0x7fffu + ((x.u >> 16) & 1u);
  return (u16)(r >> 16);
}
static __device__ __forceinline__ unsigned int pack2(float lo, float hi) {
  return (unsigned int)f2bf(lo) | ((unsigned int)f2bf(hi) << 16);
}
// Official HIP packed RNE conversion — compiler can fuse to v_cvt_pk_bf16_f32.
static __device__ __forceinline__ unsigned int pk_rn(float lo, float hi) {
  float2 f; f.x = lo; f.y = hi;
  union { __hip_bfloat162 h; unsigned int u; } v;
  v.h = __float22bfloat162_rn(f);
  return v.u;
}
// Raw v_exp_f32 (exp2). Safe: inputs bounded (|S| <= ~60), no edge cases.
#define EXP2(x) __builtin_amdgcn_exp2f(x)

static __device__ __forceinline__ float bf2f(u16 b) {
  union { unsigned int u; float f; } x; x.u = ((unsigned int)b) << 16;
  return x.f;
}
static __device__ __forceinline__ float bfu_lo(unsigned int u) {
  union { unsigned int u; float f; } x; x.u = u << 16; return x.f;
}
static __device__ __forceinline__ float bfu_hi(unsigned int u) {
  union { unsigned int u; float f; } x; x.u = u & 0xffff0000u; return x.f;
}
static __device__ __forceinline__ f4v MFMA(s8v a, s8v b, f4v c) {
  return __builtin_amdgcn_mfma_f32_16x16x32_bf16(a, b, c, 0, 0, 0);
}

#define GLOAD_LDS16(gp, lp)                                                  \
  __builtin_amdgcn_global_load_lds(                                         \
      (const __attribute__((address_space(1))) void*)(gp),                  \
      (__attribute__((address_space(3))) void*)(lp), 16, 0, 0)

// ---------------------------------------------------------------------------
// Prep: emb fp32 -> ETt: per 32-vocab tile, a 64 KB subtiled image:
//   byte(v,d) = ((v>>2)*64 + (d>>4))*128 + (v&3)*32 + (d&15)*2
// QK A-frags = contiguous 16B rows; PV B-frags via ds_read_b64_tr_b16.
// ---------------------------------------------------------------------------
__global__ __launch_bounds__(256) void cvt3_kernel(const float* __restrict__ emb,
                                                   char* __restrict__ ETt) {
  const int b = blockIdx.x, t = threadIdx.x;
  const int v0 = b * 32;
  char* outp = ETt + ((size_t)b << 16);
#pragma unroll
  for (int k = 0; k < 16; ++k) {
    int ci = t + 256 * k;       // 0..4095
    int v = ci >> 7;            // 0..31
    int d8 = ci & 127;          // d = 8*d8
    const float* s = emb + (size_t)(v0 + v) * D_DIM + d8 * 8;
    float4 a = *(const float4*)s;
    float4 bb = *(const float4*)(s + 4);
    uint4 x;
    x.x = pack2(a.x, a.y); x.y = pack2(a.z, a.w);
    x.z = pack2(bb.x, bb.y); x.w = pack2(bb.z, bb.w);
    int off = ((v >> 2) * 64 + (d8 >> 1)) * 128 + (v & 3) * 32 + (d8 & 1) * 16;
    *(uint4*)(outp + off) = x;
  }
}

// ---------------------------------------------------------------------------
// Flash v9: EXACT v8 structure/barriers (proven 615us) with two VALU deltas:
//  (1) exp2 via __builtin_amdgcn_exp2f (1 instr vs libm fixup path).
//  (2) hot-loop bf16 packing via __float22bfloat162_rn (fusable to
//      v_cvt_pk_bf16_f32).
// 512 thr = 8 waves = 4 d-slices x 2 m-halves. KV=32 per tile.
// ---------------------------------------------------------------------------
template <int NSPLIT>
__global__ __launch_bounds__(512, 2) void flash9_kernel(
    const float* __restrict__ qg, const char* __restrict__ ETt,
    float* __restrict__ out, u16* __restrict__ pctx, float* __restrict__ pstat) {
  __shared__ char ring[2 * 65536];      // 128 KB: E-tile ring (subtiled image)
  __shared__ uint2 Sred[8 * 4 * 64];    // 16 KB: bf16x4 S^T partials
  __shared__ char Plds[4096];           // 4 KB: P [mh][32 m][32 v] bf16
  __shared__ float lred[8][16];

  const int tid = threadIdx.x;
  const int w = tid >> 6;
  const int l = tid & 63;
  const int g = l >> 4;
  const int c = l & 15;
  const int ds = w & 3;                 // d-slice: [ds*256, ds*256+256)
  const int mh = w >> 2;                // m-half: rows [mh*32, mh*32+32)
  const int bid = blockIdx.x;
  const int sp = (NSPLIT == 4) ? (bid & 3) : 0;
  const int rb = (NSPLIT == 4) ? (bid >> 2) : bid;
  const int row0 = rb * MBLK;
  const int vslice = VOCABSZ / NSPLIT;
  const int ntiles = vslice / 32;       // 250 or 1000
  const int gt0 = sp * ntiles;

  const f4v fzero = {0.f, 0.f, 0.f, 0.f};

  // ---- Q fragments (B-role), pre-scaled by LOG2E so softmax is exp2-direct.
  s8v qf[2][8];
#pragma unroll
  for (int mt = 0; mt < 2; ++mt)
#pragma unroll
    for (int kt = 0; kt < 8; ++kt) {
      const float* src = qg + (size_t)(row0 + mh * 32 + 16 * mt + c) * D_DIM +
                         ds * 256 + 32 * kt + 8 * g;
      float4 a = *(const float4*)src;
      float4 b = *(const float4*)(src + 4);
      s8v v;
      v[0] = (short)f2bf(a.x * LOG2E); v[1] = (short)f2bf(a.y * LOG2E);
      v[2] = (short)f2bf(a.z * LOG2E); v[3] = (short)f2bf(a.w * LOG2E);
      v[4] = (short)f2bf(b.x * LOG2E); v[5] = (short)f2bf(b.y * LOG2E);
      v[6] = (short)f2bf(b.z * LOG2E); v[7] = (short)f2bf(b.w * LOG2E);
      qf[mt][kt] = v;
    }

  f4v acc[2][16];
#pragma unroll
  for (int mt = 0; mt < 2; ++mt)
#pragma unroll
    for (int nt = 0; nt < 16; ++nt) acc[mt][nt] = fzero;

  float lcur = 0.f;

#define STAGE(U)                                                             \
  {                                                                          \
    const char* _gs = ETt + (((size_t)(gt0 + (U))) << 16) + tid * 16;        \
    char* _ls = ring + (((U) & 1) << 16) + tid * 16;                         \
    _Pragma("unroll") for (int _j = 0; _j < 8; ++_j)                         \
        GLOAD_LDS16(_gs + _j * 8192, _ls + _j * 8192);                       \
  }

  // prologue: tile 0 staged and drained (syncthreads emits vmcnt(0))
  STAGE(0);
  __syncthreads();

  for (int t = 0; t < ntiles; ++t) {
    const char* buf = ring + ((t & 1) << 16);

    // ================= QK: S^T partial over this wave's 256-d slice =========
#pragma unroll
    for (int vt = 0; vt < 2; ++vt) {
      const char* bp = buf + (((4 * vt + (c >> 2)) * 64 + 16 * ds + (g >> 1)) * 128 +
                              (c & 3) * 32 + (g & 1) * 16);
      f4v st0 = fzero, st1 = fzero;
#pragma unroll
      for (int kt = 0; kt < 8; ++kt) {
        s8v ek = *(const s8v*)(bp + kt * 256);
        st0 = MFMA(ek, qf[0][kt], st0);
        st1 = MFMA(ek, qf[1][kt], st1);
      }
      int qb = ((mh * 4 + vt * 2) * 4 + ds) * 64 + l;
      uint2 pk;
      pk.x = pk_rn(st0[0], st0[1]); pk.y = pk_rn(st0[2], st0[3]);
      Sred[qb] = pk;
      pk.x = pk_rn(st1[0], st1[1]); pk.y = pk_rn(st1[2], st1[3]);
      Sred[qb + 256] = pk;             // mt=1 -> quadrant q+1
    }
    __syncthreads();                   // B1: Sred visible; drains prior STAGE DMA
                                       // (issued a full PV-phase ago -> hidden)

    // ================= softmax: wave (ds,mh) owns quadrant =================
    {
      int qq = mh * 4 + ds;
      f4v ss = fzero;
#pragma unroll
      for (int ww = 0; ww < 4; ++ww) {
        uint2 u = Sred[(qq * 4 + ww) * 64 + l];
        ss[0] += bfu_lo(u.x); ss[1] += bfu_hi(u.x);
        ss[2] += bfu_lo(u.y); ss[3] += bfu_hi(u.y);
      }
      float p0 = EXP2(ss[0]), p1 = EXP2(ss[1]);
      float p2 = EXP2(ss[2]), p3 = EXP2(ss[3]);
      int pb = mh * 2048 + (16 * (ds & 1) + c) * 64 + (16 * (ds >> 1) + 4 * g) * 2;
      uint2 pw; pw.x = pk_rn(p0, p1); pw.y = pk_rn(p2, p3);
      *(uint2*)(Plds + pb) = pw;
      lcur += (p0 + p1) + (p2 + p3);   // row-sum shfl deferred to epilogue
    }
    __syncthreads();                   // B2: P visible (no DMA in flight here)

    // stage next tile: in flight across PV + next QK, drained at next B1
    if (t + 1 < ntiles) STAGE(t + 1);

    // ================= PV: A = P rows (b128), B = E^T via tr-reads ==========
    {
      int pab = mh * 2048 + c * 64 + g * 16;
      s8v pa0 = *(const s8v*)(Plds + pab);
      s8v pa1 = *(const s8v*)(Plds + pab + 1024);
#pragma unroll
      for (int bb = 0; bb < 2; ++bb) {
        s4v trv[16];
#pragma unroll
        for (int k = 0; k < 8; ++k) {
          int nt = bb * 8 + k;
          const char* a0 = buf + ((2 * g) * 64 + 16 * ds + nt) * 128 + c * 2;
          asm volatile("ds_read_b64_tr_b16 %0, %1"
                       : "=v"(trv[2 * k]) : "v"((lds_p3)a0));
          asm volatile("ds_read_b64_tr_b16 %0, %1"
                       : "=v"(trv[2 * k + 1]) : "v"((lds_p3)(a0 + 8192)));
        }
        asm volatile("s_waitcnt lgkmcnt(0)" ::: "memory");
        __builtin_amdgcn_sched_barrier(0);
#pragma unroll
        for (int k = 0; k < 8; ++k) {
          int nt = bb * 8 + k;
          union { s4v s[2]; s8v v; } ev;
          ev.s[0] = trv[2 * k]; ev.s[1] = trv[2 * k + 1];
          acc[0][nt] = MFMA(pa0, ev.v, acc[0][nt]);
          acc[1][nt] = MFMA(pa1, ev.v, acc[1][nt]);
        }
      }
    }
  }
#undef STAGE

  // ---- finalize: deferred row-sum reduction, then normalize+write
  {
    float lp = lcur;
    lp += __shfl_xor(lp, 16);
    lp += __shfl_xor(lp, 32);
    __syncthreads();
    if (g == 0) lred[mh * 4 + ds][c] = lp;
  }
  __syncthreads();

  if (NSPLIT == 1) {
#pragma unroll
    for (int mt = 0; mt < 2; ++mt) {
      float inv[4];
#pragma unroll
      for (int r = 0; r < 4; ++r)
        inv[r] = 1.f / (lred[mh * 4 + mt][4 * g + r] + lred[mh * 4 + 2 + mt][4 * g + r]);
#pragma unroll
      for (int nt = 0; nt < 16; ++nt)
#pragma unroll
        for (int r = 0; r < 4; ++r) {
          size_t o = (size_t)(row0 + mh * 32 + 16 * mt + 4 * g + r) * D_DIM +
                     ds * 256 + 16 * nt + c;
          out[o] = acc[mt][nt][r] * inv[r] + qg[o];
        }
    }
  } else {
    u16* pc = pctx + (size_t)sp * NROWSZ * D_DIM;
#pragma unroll
    for (int mt = 0; mt < 2; ++mt)
#pragma unroll
      for (int nt = 0; nt < 16; ++nt)
#pragma unroll
        for (int r = 0; r < 4; ++r)
          pc[(size_t)(row0 + mh * 32 + 16 * mt + 4 * g + r) * D_DIM +
             ds * 256 + 16 * nt + c] = f2bf(acc[mt][nt][r]);
    if (ds < 2 && g == 0)
      pstat[(size_t)sp * NROWSZ + row0 + mh * 32 + 16 * ds + c] =
          lred[mh * 4 + ds][c] + lred[mh * 4 + 2 + ds][c];
  }
}

// ---------------------------------------------------------------------------
// Combine NSPLIT=4 partials: out = (sum ctx_sp) / (sum l_sp) + q
// ---------------------------------------------------------------------------
__global__ __launch_bounds__(256) void combine2_kernel(const float* __restrict__ qg,
                                                       const u16* __restrict__ pctx,
                                                       const float* __restrict__ pstat,
                                                       float* __restrict__ out) {
  const int r = blockIdx.x;
  const int t = threadIdx.x;
  float L = pstat[r] + pstat[NROWSZ + r] + pstat[2 * NROWSZ + r] + pstat[3 * NROWSZ + r];
  float inv = 1.f / L;
  size_t o = (size_t)r * D_DIM + t * 4;
  float sx = 0.f, sy = 0.f, sz = 0.f, sw = 0.f;
#pragma unroll
  for (int sp = 0; sp < 4; ++sp) {
    ushort4 u = *(const ushort4*)(pctx + (size_t)sp * NROWSZ * D_DIM + o);
    sx += bf2f(u.x); sy += bf2f(u.y); sz += bf2f(u.z); sw += bf2f(u.w);
  }
  float4 qv = *(const float4*)(qg + o);
  float4 res;
  res.x = sx * inv + qv.x;
  res.y = sy * inv + qv.y;
  res.z = sz * inv + qv.z;
  res.w = sw * inv + qv.w;
  *(float4*)(out + o) = res;
}

// ---------------------------------------------------------------------------
// Naive correctness fallback (tiny ws): one q-row per block.
// ---------------------------------------------------------------------------
__global__ __launch_bounds__(256) void naive_kernel(const float* __restrict__ qg,
                                                    const float* __restrict__ emb,
                                                    float* __restrict__ out) {
  __shared__ float s[VOCABSZ];
  __shared__ float qrow[D_DIM];
  __shared__ float lsh[4];
  const int r = blockIdx.x;
  const int t = threadIdx.x;
  for (int i = t; i < D_DIM; i += 256) qrow[i] = qg[(size_t)r * D_DIM + i];
  __syncthreads();
  float lpart = 0.f;
  for (int v = t; v < VOCABSZ; v += 256) {
    float dot = 0.f;
    for (int d = 0; d < D_DIM; d += 4) {
      float4 e = *(const float4*)(emb + (size_t)v * D_DIM + d);
      dot += qrow[d] * e.x + qrow[d + 1] * e.y + qrow[d + 2] * e.z + qrow[d + 3] * e.w;
    }
    float p = exp2f(dot * LOG2E);
    s[v] = p;
    lpart += p;
  }
  for (int o = 32; o; o >>= 1) lpart += __shfl_xor(lpart, o);
  if ((t & 63) == 0) lsh[t >> 6] = lpart;
  __syncthreads();
  float inv = 1.f / (lsh[0] + lsh[1] + lsh[2] + lsh[3]);
  float ax = 0.f, ay = 0.f, az = 0.f, aw = 0.f;
  for (int v = 0; v < VOCABSZ; ++v) {
    float p = s[v];
    float4 e = *(const float4*)(emb + (size_t)v * D_DIM + t * 4);
    ax += p * e.x; ay += p * e.y; az += p * e.z; aw += p * e.w;
  }
  size_t o = (size_t)r * D_DIM + t * 4;
  float4 qv = *(const float4*)(qg + o);
  float4 res;
  res.x = ax * inv + qv.x;
  res.y = ay * inv + qv.y;
  res.z = az * inv + qv.z;
  res.w = aw * inv + qv.w;
  *(float4*)(out + o) = res;
}

extern "C" void kernel_launch(void* const* d_in, const int* in_sizes, int n_in,
                              void* d_out, int out_size, void* d_ws, size_t ws_size,
                              hipStream_t stream) {
  const float* q = (const float*)d_in[0];
  const float* emb = (const float*)d_in[1];
  float* out = (float*)d_out;
  char* ws = (char*)d_ws;

  const size_t ETT_BYTES = 65536000ull;                      // 1000 tiles x 64 KB
  const size_t PCTX_BYTES = 4ull * NROWSZ * D_DIM * 2;       // 33,554,432
  const size_t PSTAT_BYTES = 4ull * NROWSZ * 4;              // 65,536

  if (ws_size >= ETT_BYTES + PCTX_BYTES + PSTAT_BYTES) {     // 99,155,968
    char* ETt = ws;
    u16* pctx = (u16*)(ws + ETT_BYTES);
    float* pstat = (float*)(ws + ETT_BYTES + PCTX_BYTES);
    cvt3_kernel<<<VOCABSZ / 32, 256, 0, stream>>>(emb, ETt);
    flash9_kernel<4><<<256, 512, 0, stream>>>(q, ETt, out, pctx, pstat);
    combine2_kernel<<<NROWSZ, 256, 0, stream>>>(q, pctx, pstat, out);
  } else if (ws_size >= ETT_BYTES) {
    char* ETt = ws;
    cvt3_kernel<<<VOCABSZ / 32, 256, 0, stream>>>(emb, ETt);
    flash9_kernel<1><<<NROWSZ / MBLK, 512, 0, stream>>>(q, ETt, out, nullptr, nullptr);
  } else {
    naive_kernel<<<NROWSZ, 256, 0, stream>>>(q, emb, out);
  }
}